// Round 3
// baseline (383.289 us; speedup 1.0000x reference)
//
#include <hip/hip_runtime.h>
#include <stdint.h>

#define BATCH  64
#define SEQ    2048
#define DIM    512
#define NFINE  16
#define MSPANS 512
#define STRIDE 516   // dwords; rows 16B-aligned

// ---------------------------------------------------------------------------
// Kernel A v3: one block per batch row. NO atomics.
//  - zero this row's output slice
//  - scan #1: cumsum of (label==B) -> span id per token
//  - scan #2: cumsum of valid-count -> deterministic sorted slot per token
//  - write sorted packed list (s<<16|seg); for each span's B token write
//    spanPtr[row][seg] = slot. Sentinel spanPtr[row][nspans] = vtotal.
// ---------------------------------------------------------------------------
__global__ __launch_bounds__(256) void build_spans_kernel(
    const int* __restrict__ labels,
    const int* __restrict__ pB, const int* __restrict__ pI,
    int* __restrict__ cnt,        // [0..63] vtotal, [64..127] nspans
    int* __restrict__ spanPtr,    // 64 x 513
    uint32_t* __restrict__ list,  // 64 x 2048
    float* __restrict__ out)
{
    const int row = blockIdx.x;
    const int tid = threadIdx.x;                 // 0..255
    const int Btag = *pB, Itag = *pI;

    // zero output slice for this row: 512*16 floats = 2048 float4
    float4* oz = (float4*)(out + (size_t)row * MSPANS * NFINE);
    #pragma unroll
    for (int k = 0; k < 8; ++k)
        oz[tid + k * 256] = make_float4(0.f, 0.f, 0.f, 0.f);

    // 8 labels per thread
    const int4* lab4 = (const int4*)(labels + (size_t)row * SEQ);
    int4 a = lab4[tid * 2], b = lab4[tid * 2 + 1];
    int l[8] = {a.x, a.y, a.z, a.w, b.x, b.y, b.z, b.w};

    __shared__ int scan[256];

    // ---- scan #1: B-tag counts ----
    int bcnt = 0;
    #pragma unroll
    for (int k = 0; k < 8; ++k) bcnt += (l[k] == Btag);
    scan[tid] = bcnt;
    __syncthreads();
    for (int off = 1; off < 256; off <<= 1) {
        int v = scan[tid];
        int u = (tid >= off) ? scan[tid - off] : 0;
        __syncthreads();
        scan[tid] = v + u;
        __syncthreads();
    }
    const int bexcl = (tid > 0) ? scan[tid - 1] : 0;
    const int btot  = scan[255];
    __syncthreads();

    // per-token seg + validity, count valid
    int  seg8[8];
    bool val8[8];
    bool isb8[8];
    int vcnt = 0, run = bexcl;
    #pragma unroll
    for (int k = 0; k < 8; ++k) {
        const bool isb = (l[k] == Btag);
        const bool isi = (l[k] == Itag);
        run += isb;
        const int seg = run - 1;
        const bool v = (isb | isi) && seg >= 0 && seg < MSPANS;
        seg8[k] = seg; val8[k] = v; isb8[k] = isb;
        vcnt += v;
    }

    // ---- scan #2: valid counts -> sorted slots ----
    scan[tid] = vcnt;
    __syncthreads();
    for (int off = 1; off < 256; off <<= 1) {
        int v = scan[tid];
        int u = (tid >= off) ? scan[tid - off] : 0;
        __syncthreads();
        scan[tid] = v + u;
        __syncthreads();
    }
    const int vexcl = (tid > 0) ? scan[tid - 1] : 0;
    const int vtot  = scan[255];

    uint32_t* lrow = list + (size_t)row * SEQ;
    int* sp = spanPtr + row * (MSPANS + 1);
    int slot = vexcl;
    #pragma unroll
    for (int k = 0; k < 8; ++k) {
        if (val8[k]) {
            const int s = tid * 8 + k;
            lrow[slot] = ((uint32_t)s << 16) | (uint32_t)seg8[k];
            if (isb8[k]) sp[seg8[k]] = slot;     // span's first member is its B
            ++slot;
        }
    }
    if (tid == 0) {
        const int nsp = (btot < MSPANS) ? btot : MSPANS;
        cnt[row]      = vtot;
        cnt[64 + row] = nsp;
        sp[nsp]       = vtot;                    // sentinel end
    }
}

// ---------------------------------------------------------------------------
// Kernel B v3: ONE WAVE PER SPAN, plain stores (no atomics).
// 1024 blocks x 512 threads = 8192 waves, 128 waves/row; span = wir + 128k.
// Lane layout: f = lane&15, q = lane>>4 (dim quarter). Per member token:
// 32 global float4 of the hidden row (16-way broadcast dedup) + 32 ds_read_b128
// of semb; 4 accumulators; shfl_xor(16,32) reduce; lanes 0..15 emit one
// coalesced 64B store per span.
// ---------------------------------------------------------------------------
__global__ __launch_bounds__(512) void span_score_kernel(
    const float* __restrict__ hidden,
    const float* __restrict__ semb,
    const int* __restrict__ cnt,
    const int* __restrict__ spanPtr,
    const uint32_t* __restrict__ list,
    float* __restrict__ out)
{
    __shared__ float sT[NFINE * STRIDE];         // 33 KB

    for (int i = threadIdx.x; i < DIM * NFINE; i += 512)
        sT[(i & 15) * STRIDE + (i >> 4)] = semb[i];   // semb [d][f] -> sT[f][d]
    __syncthreads();

    const int row  = blockIdx.x >> 4;            // 16 blocks per row
    const int wir  = (blockIdx.x & 15) * 8 + (threadIdx.x >> 6);  // 0..127
    const int lane = threadIdx.x & 63;
    const int f = lane & 15, q = lane >> 4;

    const int nsp = cnt[64 + row];
    const float*    hbase = hidden  + (size_t)row * SEQ * DIM;
    float*          obase = out     + (size_t)row * MSPANS * NFINE;
    const uint32_t* lrow  = list    + (size_t)row * SEQ;
    const int*      sp    = spanPtr + row * (MSPANS + 1);
    const float4*   sv    = (const float4*)&sT[f * STRIDE + q * 128];

    for (int seg = wir; seg < nsp; seg += 128) { // wave-uniform
        const int i0 = sp[seg], i1 = sp[seg + 1];
        float a0 = 0.f, a1 = 0.f, a2 = 0.f, a3 = 0.f;
        for (int i = i0; i < i1; ++i) {          // members (avg ~2.25)
            const int s = (int)(lrow[i] >> 16);
            const float4* h4 = (const float4*)(hbase + (size_t)s * DIM + q * 128);
            #pragma unroll 8
            for (int j = 0; j < 32; ++j) {
                float4 h  = h4[j];
                float4 s4 = sv[j];
                a0 = fmaf(h.x, s4.x, a0);
                a1 = fmaf(h.y, s4.y, a1);
                a2 = fmaf(h.z, s4.z, a2);
                a3 = fmaf(h.w, s4.w, a3);
            }
        }
        float acc = (a0 + a1) + (a2 + a3);
        acc += __shfl_xor(acc, 16);
        acc += __shfl_xor(acc, 32);              // lane L: full dot for f=L&15
        if (lane < NFINE) obase[seg * NFINE + lane] = acc;  // one 64B store
    }
}

extern "C" void kernel_launch(void* const* d_in, const int* in_sizes, int n_in,
                              void* d_out, int out_size, void* d_ws, size_t ws_size,
                              hipStream_t stream)
{
    const float* hidden = (const float*)d_in[0];
    const float* semb   = (const float*)d_in[1];
    const int*   labels = (const int*)d_in[2];
    const int*   pB     = (const int*)d_in[3];
    const int*   pI     = (const int*)d_in[4];
    float* out = (float*)d_out;

    // ws layout: [0,512) cnt (128 ints); [512, 512+64*513*4) spanPtr;
    //            [131840, +64*2048*4) packed sorted lists
    int*      cnt     = (int*)d_ws;
    int*      spanPtr = (int*)((char*)d_ws + 512);
    uint32_t* list    = (uint32_t*)((char*)d_ws + 131840);

    build_spans_kernel<<<BATCH, 256, 0, stream>>>(labels, pB, pI, cnt, spanPtr, list, out);
    span_score_kernel<<<BATCH * 16, 512, 0, stream>>>(hidden, semb, cnt, spanPtr, list, out);
}